// Round 10
// baseline (315.662 us; speedup 1.0000x reference)
//
#include <hip/hip_runtime.h>
#include <hip/hip_bf16.h>

#define B_    4
#define N_    8192
#define TOT   (B_*N_)      // 32768 points
#define KNN_  16
#define PPW   8            // points per wave in k2
#define PITCH 80           // LDS tile pitch in halfs (160B, 16B-aligned rows)

typedef _Float16 half8  __attribute__((ext_vector_type(8)));
typedef float    floatx4 __attribute__((ext_vector_type(4)));

#define MFMA16(A, Bv, C) __builtin_amdgcn_mfma_f32_16x16x32_f16((A), (Bv), (C), 0, 0, 0)

__device__ __forceinline__ void lds_fence(){
  asm volatile("s_waitcnt lgkmcnt(0)" ::: "memory");
}
__device__ __forceinline__ half8 h8_load_f32(const float* __restrict__ p){
  float4 a = *(const float4*)p;
  float4 b = *(const float4*)(p + 4);
  half8 r;
  r[0] = (_Float16)a.x; r[1] = (_Float16)a.y; r[2] = (_Float16)a.z; r[3] = (_Float16)a.w;
  r[4] = (_Float16)b.x; r[5] = (_Float16)b.y; r[6] = (_Float16)b.z; r[7] = (_Float16)b.w;
  return r;
}
__device__ __forceinline__ void store8f(float* __restrict__ p, half8 v){
  float4 a = {(float)v[0], (float)v[1], (float)v[2], (float)v[3]};
  float4 b = {(float)v[4], (float)v[5], (float)v[6], (float)v[7]};
  *(float4*)p = a;
  *(float4*)(p + 4) = b;
}

// Fill LDS B-fragment array for a 64x64 row-major f32 weight.
// Layout: frag index (kt*4+nt)*64 + lane; lane holds W[kt*32+quad*8+j][nt*16+(lane&15)].
__device__ void fill_w64(half8* dst, const float* __restrict__ W, int tid){
  for (int i = tid; i < 512; i += 256){
    int lane = i & 63, nt = (i >> 6) & 3, kt = i >> 8;
    int n  = nt*16 + (lane & 15);
    int kb = kt*32 + ((lane >> 4) & 3)*8;
    half8 v;
    #pragma unroll
    for (int j = 0; j < 8; j++) v[j] = (_Float16)W[(kb + j)*64 + n];
    dst[i] = v;
  }
}

// ---------------- kernel 1: x = fc1(features); q/xk/xv = x @ {wq,wk,wv} ----------------
__global__ __launch_bounds__(256, 3) void k1_qkv(
    const float* __restrict__ feat, const float* __restrict__ fc1w, const float* __restrict__ fc1b,
    const float* __restrict__ wqw, const float* __restrict__ wkw, const float* __restrict__ wvw,
    _Float16* __restrict__ qws, _Float16* __restrict__ kws, _Float16* __restrict__ vws)
{
  __shared__ half8 Sfc1[512], Sq[512], Sk[512], Sv[512];
  __shared__ alignas(16) _Float16 xt[4][16*PITCH];
  const int tid = threadIdx.x;
  fill_w64(Sfc1, fc1w, tid);
  fill_w64(Sq, wqw, tid);
  fill_w64(Sk, wkw, tid);
  fill_w64(Sv, wvw, tid);
  __syncthreads();

  const int wave = tid >> 6, lane = tid & 63, quad = lane >> 4, m16 = lane & 15;
  _Float16* tx = &xt[wave][0];
  const int rowbase = blockIdx.x*64 + wave*16;
  float fb[4];
  #pragma unroll
  for (int nt = 0; nt < 4; nt++) fb[nt] = fc1b[nt*16 + m16];

  const int arow = rowbase + m16;
  half8 Fa0 = h8_load_f32(&feat[arow*64 + quad*8]);
  half8 Fa1 = h8_load_f32(&feat[arow*64 + 32 + quad*8]);
  const floatx4 z4 = {0.f, 0.f, 0.f, 0.f};

  #pragma unroll
  for (int nt = 0; nt < 4; nt++){
    floatx4 acc = MFMA16(Fa0, Sfc1[nt*64 + lane], z4);
    acc = MFMA16(Fa1, Sfc1[(4 + nt)*64 + lane], acc);
    const int col = nt*16 + m16;
    #pragma unroll
    for (int r = 0; r < 4; r++)
      tx[(quad*4 + r)*PITCH + col] = (_Float16)(acc[r] + fb[nt]);
  }
  lds_fence();
  const half8 Ax0 = *(const half8*)&tx[m16*PITCH + quad*8];
  const half8 Ax1 = *(const half8*)&tx[m16*PITCH + 32 + quad*8];

#define EMIT_QKV(S, OUT)                                                      \
  { _Pragma("unroll")                                                         \
    for (int nt = 0; nt < 4; nt++){                                           \
      floatx4 acc = MFMA16(Ax0, S[nt*64 + lane], z4);                         \
      acc = MFMA16(Ax1, S[(4 + nt)*64 + lane], acc);                          \
      _Pragma("unroll")                                                       \
      for (int r = 0; r < 4; r++)                                             \
        OUT[(rowbase + quad*4 + r)*64 + nt*16 + m16] = (_Float16)acc[r];      \
    } }
  EMIT_QKV(Sq, qws)
  EMIT_QKV(Sk, kws)
  EMIT_QKV(Sv, vws)
#undef EMIT_QKV
}

// ---------------- kernel 2: per-point fused pos_enc / attention ----------------
// vs round 9: weight staging aliased onto the tile area (dead after the prologue
// fragment loads) -> LDS 66.5KB -> 42KB -> __launch_bounds__(256,3): 3 blocks/CU,
// 3 waves/SIMD for latency hiding. Loop body unchanged.
__global__ __launch_bounds__(256, 3) void k2_point(
    const float* __restrict__ xyz, const int* __restrict__ knn,
    const float* __restrict__ d1w, const float* __restrict__ d1b,
    const float* __restrict__ d2w, const float* __restrict__ d2b,
    const float* __restrict__ g1w, const float* __restrict__ g1b,
    const float* __restrict__ g2w, const float* __restrict__ g2b,
    const _Float16* __restrict__ qws, const _Float16* __restrict__ kws,
    const _Float16* __restrict__ vws,
    _Float16* __restrict__ r0, float* __restrict__ attn_out)
{
  __shared__ float4 Td1[64];                               // d1^T cols {w0,w1,w2,bias}
  __shared__ alignas(16) _Float16 tiles[4][2][16*PITCH];   // P/u tiles (pair A/B)
  __shared__ alignas(16) _Float16 atile[4][2][16*PITCH];   // deferred attn tiles
  const int tid = threadIdx.x;
  const int wave = tid >> 6, lane = tid & 63, quad = lane >> 4, m16 = lane & 15;

  // ---- sequential weight staging through an 8KB scratch window in the tile area ----
  half8* scratch = (half8*)&tiles[0][0][0];                // 8KB needed, 20.5KB available
  half8 Fd2[2][4], Fg1[2][4], Fg2[2][4];
  fill_w64(scratch, d2w, tid);
  if (tid < 64)
    Td1[tid] = make_float4(d1w[tid], d1w[64 + tid], d1w[128 + tid], d1b[tid]);
  __syncthreads();
  #pragma unroll
  for (int nt = 0; nt < 4; nt++)
    #pragma unroll
    for (int kt = 0; kt < 2; kt++) Fd2[kt][nt] = scratch[(kt*4 + nt)*64 + lane];
  __syncthreads();
  fill_w64(scratch, g1w, tid);
  __syncthreads();
  #pragma unroll
  for (int nt = 0; nt < 4; nt++)
    #pragma unroll
    for (int kt = 0; kt < 2; kt++) Fg1[kt][nt] = scratch[(kt*4 + nt)*64 + lane];
  __syncthreads();
  fill_w64(scratch, g2w, tid);
  __syncthreads();
  #pragma unroll
  for (int nt = 0; nt < 4; nt++)
    #pragma unroll
    for (int kt = 0; kt < 2; kt++) Fg2[kt][nt] = scratch[(kt*4 + nt)*64 + lane];
  __syncthreads();

  _Float16* tT0 = &tiles[wave][0][0];
  _Float16* tT1 = &tiles[wave][1][0];
  _Float16* aT0 = &atile[wave][0][0];
  _Float16* aT1 = &atile[wave][1][0];

  float bd2[4], bg1[4], bg2[4];
  #pragma unroll
  for (int nt = 0; nt < 4; nt++){
    const int c = nt*16 + m16;
    bd2[nt] = d2b[c]; bg1[nt] = g1b[c]; bg2[nt] = g2b[c];
  }
  const floatx4 z4 = {0.f, 0.f, 0.f, 0.f};
  // XOR bank swizzle: write col' = col ^ (quad<<3); read col' = col ^ ((m16>>2)<<3).
  const int wsw = quad << 3;
  const int swz = (quad ^ (m16 >> 2)) << 3;

  // XCD-aware bijective block swizzle (grid 1024 = 8 XCDs x 128 chunks).
  const int swb  = (blockIdx.x & 7)*128 + (blockIdx.x >> 3);
  const int gpt0 = swb*(4*PPW) + wave*PPW;          // 32 consecutive points per block
  const int b    = gpt0 >> 13;                      // N=8192; constant within block

  // ---- pair-deep pipeline for the knn -> xyz gather chain ----
  int growA = b*N_ + knn[gpt0*KNN_ + m16];
  int growB = b*N_ + knn[(gpt0+1)*KNN_ + m16];
  float xqA0 = xyz[gpt0*3+0],     xqA1 = xyz[gpt0*3+1],     xqA2 = xyz[gpt0*3+2];
  float xqB0 = xyz[(gpt0+1)*3+0], xqB1 = xyz[(gpt0+1)*3+1], xqB2 = xyz[(gpt0+1)*3+2];
  float xnA0 = xyz[growA*3+0], xnA1 = xyz[growA*3+1], xnA2 = xyz[growA*3+2];
  float xnB0 = xyz[growB*3+0], xnB1 = xyz[growB*3+1], xnB2 = xyz[growB*3+2];

  int prevA = -1, prevB = -1;   // previous pair's points (deferred attn store)

  for (int pp = 0; pp < PPW; pp += 2){
    const int gptA = gpt0 + pp, gptB = gptA + 1;
    const int gA = growA, gB = growB;

    // ---- K/Q gathers, A-layout coalesced (16B/lane) ----
    const half8 KaA0 = *(const half8*)&kws[gA*64 + quad*8];
    const half8 KaA1 = *(const half8*)&kws[gA*64 + 32 + quad*8];
    const half8 QaA0 = *(const half8*)&qws[gptA*64 + quad*8];
    const half8 QaA1 = *(const half8*)&qws[gptA*64 + 32 + quad*8];
    const half8 KaB0 = *(const half8*)&kws[gB*64 + quad*8];
    const half8 KaB1 = *(const half8*)&kws[gB*64 + 32 + quad*8];
    const half8 QaB0 = *(const half8*)&qws[gptB*64 + quad*8];
    const half8 QaB1 = *(const half8*)&qws[gptB*64 + 32 + quad*8];

    // ---- V gathers in C-layout (this lane owns neighbor rows quad*4+r) ----
    const int gA0 = __shfl(gA, quad*4 + 0), gA1 = __shfl(gA, quad*4 + 1);
    const int gA2 = __shfl(gA, quad*4 + 2), gA3 = __shfl(gA, quad*4 + 3);
    const int gB0 = __shfl(gB, quad*4 + 0), gB1 = __shfl(gB, quad*4 + 1);
    const int gB2 = __shfl(gB, quad*4 + 2), gB3 = __shfl(gB, quad*4 + 3);
    _Float16 VcA[4][4], VcB[4][4];                 // [nt][r]
    #pragma unroll
    for (int nt = 0; nt < 4; nt++){
      const int c = nt*16 + m16;
      VcA[nt][0] = vws[gA0*64 + c]; VcA[nt][1] = vws[gA1*64 + c];
      VcA[nt][2] = vws[gA2*64 + c]; VcA[nt][3] = vws[gA3*64 + c];
      VcB[nt][0] = vws[gB0*64 + c]; VcB[nt][1] = vws[gB1*64 + c];
      VcB[nt][2] = vws[gB2*64 + c]; VcB[nt][3] = vws[gB3*64 + c];
    }

    // prefetch next pair's knn rows
    int growA_n = 0, growB_n = 0;
    if (pp < PPW-2){
      growA_n = b*N_ + knn[(gptA+2)*KNN_ + m16];
      growB_n = b*N_ + knn[(gptB+2)*KNN_ + m16];
    }

    const float dxA = xqA0 - xnA0, dyA = xqA1 - xnA1, dzA = xqA2 - xnA2;
    const float dxB = xqB0 - xnB0, dyB = xqB1 - xnB1, dzB = xqB2 - xnB2;

    // ---- stage 1 (both): t = relu(rel @ d1 + b), pure VALU ----
    half8 AtA0, AtA1, AtB0, AtB1;
    #pragma unroll
    for (int j = 0; j < 8; j++){
      const float4 w  = Td1[quad*8 + j];
      const float4 w2 = Td1[32 + quad*8 + j];
      float tA  = fmaf(dxA, w.x,  fmaf(dyA, w.y,  fmaf(dzA, w.z,  w.w)));
      float tA2 = fmaf(dxA, w2.x, fmaf(dyA, w2.y, fmaf(dzA, w2.z, w2.w)));
      float tB  = fmaf(dxB, w.x,  fmaf(dyB, w.y,  fmaf(dzB, w.z,  w.w)));
      float tB2 = fmaf(dxB, w2.x, fmaf(dyB, w2.y, fmaf(dzB, w2.z, w2.w)));
      AtA0[j] = (_Float16)(tA  > 0.f ? tA  : 0.f);
      AtA1[j] = (_Float16)(tA2 > 0.f ? tA2 : 0.f);
      AtB0[j] = (_Float16)(tB  > 0.f ? tB  : 0.f);
      AtB1[j] = (_Float16)(tB2 > 0.f ? tB2 : 0.f);
    }

    // ---- stage 2 (both): P = t @ d2 + b -> Pc regs + tiles ----
    float PcA[4][4], PcB[4][4];
    #pragma unroll
    for (int nt = 0; nt < 4; nt++){
      floatx4 accA = MFMA16(AtA0, Fd2[0][nt], z4);
      accA = MFMA16(AtA1, Fd2[1][nt], accA);
      floatx4 accB = MFMA16(AtB0, Fd2[0][nt], z4);
      accB = MFMA16(AtB1, Fd2[1][nt], accB);
      const int colS = (nt*16 + m16) ^ wsw;
      #pragma unroll
      for (int r = 0; r < 4; r++){
        PcA[nt][r] = accA[r] + bd2[nt];
        PcB[nt][r] = accB[r] + bd2[nt];
        tT0[(quad*4 + r)*PITCH + colS] = (_Float16)PcA[nt][r];
        tT1[(quad*4 + r)*PITCH + colS] = (_Float16)PcB[nt][r];
      }
    }
    lds_fence();                                            // fence 1

    // ---- deferred attn store of the PREVIOUS pair (reads covered by fence 1;
    //      global-store latency hides under stages 3-4) ----
    if (prevA >= 0){
      const half8 pA0 = *(const half8*)&aT0[m16*PITCH + swz];
      const half8 pA1 = *(const half8*)&aT0[m16*PITCH + 32 + swz];
      const half8 pB0 = *(const half8*)&aT1[m16*PITCH + swz];
      const half8 pB1 = *(const half8*)&aT1[m16*PITCH + 32 + swz];
      float* apA = attn_out + ((size_t)prevA*KNN_ + m16)*64;
      store8f(apA + quad*8, pA0);
      store8f(apA + 32 + quad*8, pA1);
      float* apB = attn_out + ((size_t)prevB*KNN_ + m16)*64;
      store8f(apB + quad*8, pB0);
      store8f(apB + 32 + quad*8, pB1);
    }

    const half8 PaA0 = *(const half8*)&tT0[m16*PITCH + swz];
    const half8 PaA1 = *(const half8*)&tT0[m16*PITCH + 32 + swz];
    const half8 PaB0 = *(const half8*)&tT1[m16*PITCH + swz];
    const half8 PaB1 = *(const half8*)&tT1[m16*PITCH + 32 + swz];
    const half8 HA0 = QaA0 - KaA0 + PaA0;
    const half8 HA1 = QaA1 - KaA1 + PaA1;
    const half8 HB0 = QaB0 - KaB0 + PaB0;
    const half8 HB1 = QaB1 - KaB1 + PaB1;

    // ---- stage 3 (both): u = relu(H @ g1 + b) -> tiles ----
    #pragma unroll
    for (int nt = 0; nt < 4; nt++){
      floatx4 accA = MFMA16(HA0, Fg1[0][nt], z4);
      accA = MFMA16(HA1, Fg1[1][nt], accA);
      floatx4 accB = MFMA16(HB0, Fg1[0][nt], z4);
      accB = MFMA16(HB1, Fg1[1][nt], accB);
      const int colS = (nt*16 + m16) ^ wsw;
      #pragma unroll
      for (int r = 0; r < 4; r++){
        float tA = accA[r] + bg1[nt];
        float tB = accB[r] + bg1[nt];
        tT0[(quad*4 + r)*PITCH + colS] = (_Float16)(tA > 0.f ? tA : 0.f);
        tT1[(quad*4 + r)*PITCH + colS] = (_Float16)(tB > 0.f ? tB : 0.f);
      }
    }
    lds_fence();                                            // fence 2
    const half8 UA0 = *(const half8*)&tT0[m16*PITCH + swz];
    const half8 UA1 = *(const half8*)&tT0[m16*PITCH + 32 + swz];
    const half8 UB0 = *(const half8*)&tT1[m16*PITCH + swz];
    const half8 UB1 = *(const half8*)&tT1[m16*PITCH + 32 + swz];

    // ---- stage 4 (both): logits = u @ g2 + b -> softmax in C-layout regs ----
    float A2A[4][4], A2B[4][4];
    #pragma unroll
    for (int nt = 0; nt < 4; nt++){
      floatx4 accA = MFMA16(UA0, Fg2[0][nt], z4);
      accA = MFMA16(UA1, Fg2[1][nt], accA);
      floatx4 accB = MFMA16(UB0, Fg2[0][nt], z4);
      accB = MFMA16(UB1, Fg2[1][nt], accB);
      #pragma unroll
      for (int r = 0; r < 4; r++){ A2A[nt][r] = accA[r] + bg2[nt]; A2B[nt][r] = accB[r] + bg2[nt]; }
    }
    #pragma unroll
    for (int nt = 0; nt < 4; nt++){
      float mxA = fmaxf(fmaxf(A2A[nt][0], A2A[nt][1]), fmaxf(A2A[nt][2], A2A[nt][3]));
      float mxB = fmaxf(fmaxf(A2B[nt][0], A2B[nt][1]), fmaxf(A2B[nt][2], A2B[nt][3]));
      mxA = fmaxf(mxA, __shfl_xor(mxA, 16));
      mxB = fmaxf(mxB, __shfl_xor(mxB, 16));
      mxA = fmaxf(mxA, __shfl_xor(mxA, 32));
      mxB = fmaxf(mxB, __shfl_xor(mxB, 32));
      float sA = 0.f, sB = 0.f;
      #pragma unroll
      for (int r = 0; r < 4; r++){
        float eA = exp2f((A2A[nt][r] - mxA)*0.18033688011112042f);  // /8, base-2
        float eB = exp2f((A2B[nt][r] - mxB)*0.18033688011112042f);
        A2A[nt][r] = eA; sA += eA;
        A2B[nt][r] = eB; sB += eB;
      }
      sA += __shfl_xor(sA, 16);
      sB += __shfl_xor(sB, 16);
      sA += __shfl_xor(sA, 32);
      sB += __shfl_xor(sB, 32);
      const float invA = __builtin_amdgcn_rcpf(sA);
      const float invB = __builtin_amdgcn_rcpf(sB);
      #pragma unroll
      for (int r = 0; r < 4; r++){ A2A[nt][r] *= invA; A2B[nt][r] *= invB; }
      // stash normalized attn into the deferred-store tiles (no fence here)
      const int colS = (nt*16 + m16) ^ wsw;
      #pragma unroll
      for (int r = 0; r < 4; r++){
        aT0[(quad*4 + r)*PITCH + colS] = (_Float16)A2A[nt][r];
        aT1[(quad*4 + r)*PITCH + colS] = (_Float16)A2B[nt][r];
      }
    }

    // ---- res0 in C-layout: sum over nb = quad*4+r then cross-quad (2 shuffles) ----
    #pragma unroll
    for (int nt = 0; nt < 4; nt++){
      float sA = A2A[nt][0]*((float)VcA[nt][0] + PcA[nt][0])
               + A2A[nt][1]*((float)VcA[nt][1] + PcA[nt][1])
               + A2A[nt][2]*((float)VcA[nt][2] + PcA[nt][2])
               + A2A[nt][3]*((float)VcA[nt][3] + PcA[nt][3]);
      float sB = A2B[nt][0]*((float)VcB[nt][0] + PcB[nt][0])
               + A2B[nt][1]*((float)VcB[nt][1] + PcB[nt][1])
               + A2B[nt][2]*((float)VcB[nt][2] + PcB[nt][2])
               + A2B[nt][3]*((float)VcB[nt][3] + PcB[nt][3]);
      sA += __shfl_xor(sA, 16);
      sB += __shfl_xor(sB, 16);
      sA += __shfl_xor(sA, 32);
      sB += __shfl_xor(sB, 32);
      if (quad == 0){
        r0[gptA*64 + nt*16 + m16] = (_Float16)sA;
        r0[gptB*64 + nt*16 + m16] = (_Float16)sB;
      }
    }

    prevA = gptA; prevB = gptB;

    // ---- next pair's xyz loads (knn results have had a full body to land) ----
    if (pp < PPW-2){
      growA = growA_n; growB = growB_n;
      xqA0 = xyz[(gptA+2)*3+0]; xqA1 = xyz[(gptA+2)*3+1]; xqA2 = xyz[(gptA+2)*3+2];
      xqB0 = xyz[(gptB+2)*3+0]; xqB1 = xyz[(gptB+2)*3+1]; xqB2 = xyz[(gptB+2)*3+2];
      xnA0 = xyz[growA_n*3+0]; xnA1 = xyz[growA_n*3+1]; xnA2 = xyz[growA_n*3+2];
      xnB0 = xyz[growB_n*3+0]; xnB1 = xyz[growB_n*3+1]; xnB2 = xyz[growB_n*3+2];
    }
  }

  // ---- drain: store the final pair's attn ----
  lds_fence();
  {
    const half8 pA0 = *(const half8*)&aT0[m16*PITCH + swz];
    const half8 pA1 = *(const half8*)&aT0[m16*PITCH + 32 + swz];
    const half8 pB0 = *(const half8*)&aT1[m16*PITCH + swz];
    const half8 pB1 = *(const half8*)&aT1[m16*PITCH + 32 + swz];
    float* apA = attn_out + ((size_t)prevA*KNN_ + m16)*64;
    store8f(apA + quad*8, pA0);
    store8f(apA + 32 + quad*8, pA1);
    float* apB = attn_out + ((size_t)prevB*KNN_ + m16)*64;
    store8f(apB + quad*8, pB0);
    store8f(apB + 32 + quad*8, pB1);
  }
}

// ---------------- kernel 3: res = res0 @ fc2 + fc2_b + features ----------------
__global__ __launch_bounds__(256, 2) void k3_fc2(
    const _Float16* __restrict__ r0, const float* __restrict__ fc2w,
    const float* __restrict__ fc2b, const float* __restrict__ feat,
    float* __restrict__ out_res)
{
  __shared__ half8 S[512];
  const int tid = threadIdx.x;
  fill_w64(S, fc2w, tid);
  __syncthreads();

  const int wave = tid >> 6, lane = tid & 63, quad = lane >> 4, m16 = lane & 15;
  const int rowbase = blockIdx.x*64 + wave*16;
  float fb[4];
  #pragma unroll
  for (int nt = 0; nt < 4; nt++) fb[nt] = fc2b[nt*16 + m16];

  const half8 A0 = *(const half8*)&r0[(rowbase + m16)*64 + quad*8];
  const half8 A1 = *(const half8*)&r0[(rowbase + m16)*64 + 32 + quad*8];
  const floatx4 z4 = {0.f, 0.f, 0.f, 0.f};

  #pragma unroll
  for (int nt = 0; nt < 4; nt++){
    floatx4 acc = MFMA16(A0, S[nt*64 + lane], z4);
    acc = MFMA16(A1, S[(4 + nt)*64 + lane], acc);
    #pragma unroll
    for (int r = 0; r < 4; r++){
      const int rowg = rowbase + quad*4 + r;
      const int col  = nt*16 + m16;
      out_res[rowg*64 + col] = acc[r] + fb[nt] + feat[rowg*64 + col];
    }
  }
}

extern "C" void kernel_launch(void* const* d_in, const int* in_sizes, int n_in,
                              void* d_out, int out_size, void* d_ws, size_t ws_size,
                              hipStream_t stream)
{
  (void)in_sizes; (void)n_in; (void)out_size; (void)ws_size;
  const float* xyz  = (const float*)d_in[0];
  const float* feat = (const float*)d_in[1];
  const int*   knn  = (const int*)d_in[2];
  const float* fc1w = (const float*)d_in[3];
  const float* fc1b = (const float*)d_in[4];
  const float* fc2w = (const float*)d_in[5];
  const float* fc2b = (const float*)d_in[6];
  const float* d1w  = (const float*)d_in[7];
  const float* d1b  = (const float*)d_in[8];
  const float* d2w  = (const float*)d_in[9];
  const float* d2b  = (const float*)d_in[10];
  const float* g1w  = (const float*)d_in[11];
  const float* g1b  = (const float*)d_in[12];
  const float* g2w  = (const float*)d_in[13];
  const float* g2b  = (const float*)d_in[14];
  const float* wq   = (const float*)d_in[15];
  const float* wk   = (const float*)d_in[16];
  const float* wv   = (const float*)d_in[17];

  _Float16* ws  = (_Float16*)d_ws;
  _Float16* qws = ws;                      // TOT*64 halfs
  _Float16* kws = ws + (size_t)TOT*64;
  _Float16* vws = ws + (size_t)2*TOT*64;
  _Float16* r0  = ws + (size_t)3*TOT*64;

  float* out      = (float*)d_out;
  float* out_res  = out;                     // (B,N,64)
  float* out_attn = out + (size_t)TOT*64;    // (B,N,K,64)

  k1_qkv<<<TOT/64, 256, 0, stream>>>(feat, fc1w, fc1b, wq, wk, wv, qws, kws, vws);
  k2_point<<<TOT/(4*PPW), 256, 0, stream>>>(xyz, knn, d1w, d1b, d2w, d2b,
                                            g1w, g1b, g2w, g2b,
                                            qws, kws, vws, r0, out_attn);
  k3_fc2<<<TOT/64, 256, 0, stream>>>(r0, fc2w, fc2b, feat, out_res);
}